// Round 4
// baseline (1264.920 us; speedup 1.0000x reference)
//
#include <hip/hip_runtime.h>
#include <hip/hip_bf16.h>
#include <math.h>
#include <stdint.h>

// SparseMoE: B=4, L=2048 -> T=8192 tokens, D=1024, FFN=4096, E=8, topk=2.
// R4 (= R3 resubmit after infra failure): unified 256x256-tile 8-wave double-buffered
// 2-phase GEMM cores, all operands staged via global_load_lds(16B) (x pre-converted
// to bf16); nt-fastest XCD-chunked order for L2 A-reuse; ybuf+combine (no atomics).
#define T_TOKENS 8192
#define DM 1024
#define FFNDIM 4096
#define NE 8
#define CAP 8192
#define SMAX 18432            // >= 16384 + 8*255, 256-aligned

typedef __attribute__((ext_vector_type(8))) __bf16 bf16x8;
typedef __attribute__((ext_vector_type(4))) __bf16 bf16x4;
typedef __attribute__((ext_vector_type(4))) float f32x4;

__device__ __forceinline__ float gelu_exact(float v) {
    return 0.5f * v * (1.0f + erff(v * 0.70710678118654752440f));
}

union PK8 { __bf16 h[8]; uint4 v; };

// 16B global->LDS DMA. LDS dest is WAVE-UNIFORM base; HW writes base + lane*16.
// Global src is per-lane (gather + swizzle live on the source side).
__device__ __forceinline__ void gload16(const void* g, void* l) {
    __builtin_amdgcn_global_load_lds(
        (const __attribute__((address_space(1))) uint32_t*)g,
        (__attribute__((address_space(3))) uint32_t*)l, 16, 0, 0);
}

// Bijective XCD-chunked swizzle (m204 form, valid for any nwg).
__device__ __forceinline__ int xcd_swz(int nwg) {
    int orig = blockIdx.x;
    int xcd = orig & 7, loc = orig >> 3;
    int q = nwg >> 3, r = nwg & 7;
    int base = (xcd < r) ? xcd * (q + 1) : r * (q + 1) + (xcd - r) * q;
    return base + loc;
}

// ---------------- tiny utility kernels ----------------
__global__ void zero_counts_kernel(int* __restrict__ counts) {
    if (threadIdx.x < NE) counts[threadIdx.x] = 0;
}

__global__ __launch_bounds__(256) void zero_out_kernel(float* __restrict__ out,
                                                       int* __restrict__ counts) {
    size_t i = (size_t)blockIdx.x * 256 + threadIdx.x;
    uint4 z = make_uint4(0u, 0u, 0u, 0u);
    uint4* p = (uint4*)out + i * 2;
    p[0] = z; p[1] = z;
    if (blockIdx.x == 0 && threadIdx.x < NE) counts[threadIdx.x] = 0;
}

__global__ __launch_bounds__(256) void cvt_x_kernel(const float* __restrict__ x,
                                                    __bf16* __restrict__ xb) {
    size_t i = ((size_t)blockIdx.x * 256 + threadIdx.x) * 8;
    f32x4 a = *(const f32x4*)(x + i);
    f32x4 b = *(const f32x4*)(x + i + 4);
    PK8 u;
#pragma unroll
    for (int j = 0; j < 4; ++j) { u.h[j] = (__bf16)a[j]; u.h[4 + j] = (__bf16)b[j]; }
    *(uint4*)(xb + i) = u.v;
}

// ---------------- prepass: w [E][K][N] f32 -> wt [E][N][K] bf16 ----------------
__global__ __launch_bounds__(256) void transpose_cvt_kernel(
        const float* __restrict__ w, __bf16* __restrict__ wt, int K, int N) {
    __shared__ __bf16 tile[64][72];
    int ntb = blockIdx.x, ktb = blockIdx.y, e = blockIdx.z;
    const float* src = w + ((size_t)e * K + (size_t)ktb * 64) * N + ntb * 64;
    int t = threadIdx.x;
    int tx = t & 15, ty = t >> 4;
#pragma unroll
    for (int rr = 0; rr < 4; ++rr) {
        int r = ty + rr * 16;
        f32x4 v = *(const f32x4*)(src + (size_t)r * N + tx * 4);
#pragma unroll
        for (int j = 0; j < 4; ++j) tile[tx * 4 + j][r] = (__bf16)v[j];
    }
    __syncthreads();
    int ow = t & 7, oy = t >> 3;
#pragma unroll
    for (int rr = 0; rr < 2; ++rr) {
        int n = oy + rr * 32;
        uint4 val = *(const uint4*)&tile[n][ow * 8];
        *(uint4*)(wt + ((size_t)e * N + (size_t)ntb * 64 + n) * K
                  + (size_t)ktb * 64 + ow * 8) = val;
    }
}

// ---------------- router ----------------
__global__ __launch_bounds__(256) void router_kernel(
        const float* __restrict__ x, const float* __restrict__ gate_w,
        const float* __restrict__ gate_b, int* __restrict__ counts,
        int* __restrict__ idx_list, float* __restrict__ gate_list,
        uint32_t* __restrict__ pack) {
    int wave = threadIdx.x >> 6, lane = threadIdx.x & 63;
    int tk = blockIdx.x * 4 + wave;
    const float* xr = x + (size_t)tk * DM;
    float acc[NE];
#pragma unroll
    for (int e = 0; e < NE; ++e) acc[e] = 0.f;
#pragma unroll
    for (int i = 0; i < DM / 64; ++i) {
        int d = i * 64 + lane;
        float xv = xr[d];
        f32x4 g0v = *(const f32x4*)(gate_w + d * NE);
        f32x4 g1v = *(const f32x4*)(gate_w + d * NE + 4);
#pragma unroll
        for (int e = 0; e < 4; ++e) { acc[e] += xv * g0v[e]; acc[4 + e] += xv * g1v[e]; }
    }
#pragma unroll
    for (int e = 0; e < NE; ++e) {
#pragma unroll
        for (int m = 32; m > 0; m >>= 1) acc[e] += __shfl_xor(acc[e], m, 64);
    }
    if (lane == 0) {
        float v0 = -INFINITY, v1 = -INFINITY;
        int i0 = 0, i1 = 0;
#pragma unroll
        for (int e = 0; e < NE; ++e) {
            float l = acc[e] + gate_b[e];
            if (l > v0) { v1 = v0; i1 = i0; v0 = l; i0 = e; }
            else if (l > v1) { v1 = l; i1 = e; }
        }
        float g0 = 1.f / (1.f + expf(v1 - v0));
        float g1 = 1.f - g0;
        int p0 = atomicAdd(&counts[i0], 1);
        idx_list[i0 * CAP + p0] = tk;
        gate_list[i0 * CAP + p0] = g0;
        int p1 = atomicAdd(&counts[i1], 1);
        idx_list[i1 * CAP + p1] = tk;
        gate_list[i1 * CAP + p1] = g1;
        pack[tk] = ((uint32_t)((i0 << 13) | p0) << 16) | (uint32_t)((i1 << 13) | p1);
    }
}

// ---------------- scan: 256-aligned prefix ----------------
__global__ void scan_kernel(const int* __restrict__ counts, int* __restrict__ pbase) {
    if (threadIdx.x == 0 && blockIdx.x == 0) {
        int s = 0;
        for (int e = 0; e < NE; ++e) { pbase[e] = s; s += (counts[e] + 255) & ~255; }
        pbase[NE] = s;
    }
}

__device__ __forceinline__ int find_expert(const int* pbase, int slot_tile) {
    int e = 0;
#pragma unroll
    for (int k = 0; k < NE - 1; ++k)
        if (pbase[k + 1] <= slot_tile) e = k + 1;
    return e;
}

// ======== unified 256x256 GEMM core (8 waves, BK=32, dbuf 2-phase) ========
// LDS: Al/Bl [2][256 rows][32 k] bf16, 64 KB total -> 1 block/CU, 256-VGPR budget.
// Stage: per thread 2 A-segs + 2 B-segs of 16B; dest wave-uniform (wave*2+q)*1024 ->
// HW row=(wave*2+q)*16+(lane>>2), chunk=lane&3. XOR involution slot = ch ^ ((row>>1)&3)
// applied on SOURCE addr and READ addr (rule #21 both-sides).

// ---------------- gemm1: h = gelu(xb[tok] @ w1t[e] + b1[e]) ----------------
__global__ __launch_bounds__(512, 2) void gemm1_kernel(
        const __bf16* __restrict__ xb, const __bf16* __restrict__ w1t,
        const float* __restrict__ b1, const int* __restrict__ counts,
        const int* __restrict__ pbase, const int* __restrict__ idx_list,
        __bf16* __restrict__ h, int chunk_start) {
    __shared__ __bf16 Al[2][256 * 32];
    __shared__ __bf16 Bl[2][256 * 32];

    int wid = xcd_swz(gridDim.x);
    int mtl = wid >> 4, nt = wid & 15;          // nt-fastest: A reused across nt in L2

    int slot_tile = chunk_start + mtl * 256;
    if (slot_tile >= pbase[NE]) return;
    int e = find_expert(pbase, slot_tile);
    int cnt = counts[e];
    int loc = slot_tile - pbase[e];
    if (loc >= cnt) return;

    int t = threadIdx.x, lane = t & 63, wave = t >> 6;

    const char* asrc[2];
    const char* bsrc[2];
    uint32_t dofs[2];
#pragma unroll
    for (int q = 0; q < 2; ++q) {
        int row = (wave * 2 + q) * 16 + (lane >> 2);
        int ch  = lane & 3;
        int sw  = ((ch ^ ((row >> 1) & 3)) << 4);
        int lc = loc + row; if (lc > cnt - 1) lc = cnt - 1;
        int tok = idx_list[e * CAP + lc];
        asrc[q] = (const char*)(xb + (size_t)tok * DM) + sw;
        bsrc[q] = (const char*)(w1t + ((size_t)e * FFNDIM + nt * 256 + row) * DM) + sw;
        dofs[q] = (uint32_t)(wave * 2 + q) * 1024;   // wave-uniform LDS byte offset
    }

    int wr = wave >> 2, wc = wave & 3;               // 2x4 wave grid: 128m x 64n each
    int l15 = lane & 15, quad = lane >> 4;

    f32x4 acc[8][4];
#pragma unroll
    for (int i = 0; i < 8; ++i)
#pragma unroll
        for (int j = 0; j < 4; ++j) acc[i][j] = f32x4{0.f, 0.f, 0.f, 0.f};

    // prologue: stage step 0 into buf 0
#pragma unroll
    for (int q = 0; q < 2; ++q) {
        gload16(asrc[q], (char*)Al[0] + dofs[q]);
        gload16(bsrc[q], (char*)Bl[0] + dofs[q]);
    }
    __syncthreads();

    const int NSTEP = DM / 32;                       // 32 steps
    for (int st = 0; st < NSTEP; ++st) {
        int cur = st & 1;
        if (st + 1 < NSTEP) {
            int off = (st + 1) * 64;                 // 32 bf16 = 64 B per step
#pragma unroll
            for (int q = 0; q < 2; ++q) {
                gload16(asrc[q] + off, (char*)Al[cur ^ 1] + dofs[q]);
                gload16(bsrc[q] + off, (char*)Bl[cur ^ 1] + dofs[q]);
            }
        }
        const __bf16* A = Al[cur];
        const __bf16* B = Bl[cur];
        bf16x8 af[8], bfr[4];
#pragma unroll
        for (int i = 0; i < 8; ++i) {
            int m = wr * 128 + i * 16 + l15;
            af[i] = *(const bf16x8*)(A + m * 32 + ((quad ^ ((m >> 1) & 3)) << 3));
        }
#pragma unroll
        for (int j = 0; j < 4; ++j) {
            int n = wc * 64 + j * 16 + l15;
            bfr[j] = *(const bf16x8*)(B + n * 32 + ((quad ^ ((n >> 1) & 3)) << 3));
        }
#pragma unroll
        for (int i = 0; i < 8; ++i)
#pragma unroll
            for (int j = 0; j < 4; ++j)
                acc[i][j] = __builtin_amdgcn_mfma_f32_16x16x32_bf16(
                    af[i], bfr[j], acc[i][j], 0, 0, 0);
        __syncthreads();   // drains staged loads; protects buf[cur] for next stage
    }

    float bias[4];
#pragma unroll
    for (int j = 0; j < 4; ++j)
        bias[j] = b1[(size_t)e * FFNDIM + nt * 256 + wc * 64 + j * 16 + l15];
#pragma unroll
    for (int i = 0; i < 8; ++i) {
#pragma unroll
        for (int r = 0; r < 4; ++r) {
            int rowl = wr * 128 + i * 16 + quad * 4 + r;
            if (loc + rowl < cnt) {
                size_t hoff = (size_t)(mtl * 256 + rowl) * FFNDIM + nt * 256;
#pragma unroll
                for (int j = 0; j < 4; ++j) {
                    float v = acc[i][j][r] + bias[j];
                    h[hoff + wc * 64 + j * 16 + l15] = (__bf16)gelu_exact(v);
                }
            }
        }
    }
}

// ---------------- gemm2: y[slot] = gate*(h_slot @ w2t[e] + b2) ----------------
// YM: 0 = atomicAdd into out, 1 = f32 ybuf, 2 = bf16 ybuf.
template<int YM>
__global__ __launch_bounds__(512, 2) void gemm2_kernel(
        const __bf16* __restrict__ h, const __bf16* __restrict__ w2t,
        const float* __restrict__ b2, const int* __restrict__ counts,
        const int* __restrict__ pbase, const int* __restrict__ idx_list,
        const float* __restrict__ gate_list, float* __restrict__ out,
        void* __restrict__ ybuf, int chunk_start) {
    __shared__ __bf16 Al[2][256 * 32];
    __shared__ __bf16 Bl[2][256 * 32];

    int wid = xcd_swz(gridDim.x);
    int mtl = wid >> 2, nt = wid & 3;               // nt-fastest (4 nt over DM)

    int slot_tile = chunk_start + mtl * 256;
    if (slot_tile >= pbase[NE]) return;
    int e = find_expert(pbase, slot_tile);
    int cnt = counts[e];
    int loc = slot_tile - pbase[e];
    if (loc >= cnt) return;

    int t = threadIdx.x, lane = t & 63, wave = t >> 6;

    const char* asrc[2];
    const char* bsrc[2];
    uint32_t dofs[2];
#pragma unroll
    for (int q = 0; q < 2; ++q) {
        int row = (wave * 2 + q) * 16 + (lane >> 2);
        int ch  = lane & 3;
        int sw  = ((ch ^ ((row >> 1) & 3)) << 4);
        asrc[q] = (const char*)(h + (size_t)(mtl * 256 + row) * FFNDIM) + sw;
        bsrc[q] = (const char*)(w2t + ((size_t)e * DM + nt * 256 + row) * FFNDIM) + sw;
        dofs[q] = (uint32_t)(wave * 2 + q) * 1024;
    }

    int wr = wave >> 2, wc = wave & 3;
    int l15 = lane & 15, quad = lane >> 4;

    f32x4 acc[8][4];
#pragma unroll
    for (int i = 0; i < 8; ++i)
#pragma unroll
        for (int j = 0; j < 4; ++j) acc[i][j] = f32x4{0.f, 0.f, 0.f, 0.f};

#pragma unroll
    for (int q = 0; q < 2; ++q) {
        gload16(asrc[q], (char*)Al[0] + dofs[q]);
        gload16(bsrc[q], (char*)Bl[0] + dofs[q]);
    }
    __syncthreads();

    const int NSTEP = FFNDIM / 32;                   // 128 steps
    for (int st = 0; st < NSTEP; ++st) {
        int cur = st & 1;
        if (st + 1 < NSTEP) {
            int off = (st + 1) * 64;
#pragma unroll
            for (int q = 0; q < 2; ++q) {
                gload16(asrc[q] + off, (char*)Al[cur ^ 1] + dofs[q]);
                gload16(bsrc[q] + off, (char*)Bl[cur ^ 1] + dofs[q]);
            }
        }
        const __bf16* A = Al[cur];
        const __bf16* B = Bl[cur];
        bf16x8 af[8], bfr[4];
#pragma unroll
        for (int i = 0; i < 8; ++i) {
            int m = wr * 128 + i * 16 + l15;
            af[i] = *(const bf16x8*)(A + m * 32 + ((quad ^ ((m >> 1) & 3)) << 3));
        }
#pragma unroll
        for (int j = 0; j < 4; ++j) {
            int n = wc * 64 + j * 16 + l15;
            bfr[j] = *(const bf16x8*)(B + n * 32 + ((quad ^ ((n >> 1) & 3)) << 3));
        }
#pragma unroll
        for (int i = 0; i < 8; ++i)
#pragma unroll
            for (int j = 0; j < 4; ++j)
                acc[i][j] = __builtin_amdgcn_mfma_f32_16x16x32_bf16(
                    af[i], bfr[j], acc[i][j], 0, 0, 0);
        __syncthreads();
    }

    float b2v[4];
#pragma unroll
    for (int j = 0; j < 4; ++j)
        b2v[j] = b2[(size_t)e * DM + nt * 256 + wc * 64 + j * 16 + l15];
#pragma unroll
    for (int i = 0; i < 8; ++i) {
#pragma unroll
        for (int r = 0; r < 4; ++r) {
            int rowl = wr * 128 + i * 16 + quad * 4 + r;
            int local = loc + rowl;
            if (local < cnt) {
                float g = gate_list[e * CAP + local];
                if (YM == 0) {
                    int tok = idx_list[e * CAP + local];
                    float* orow = out + (size_t)tok * DM + nt * 256;
#pragma unroll
                    for (int j = 0; j < 4; ++j)
                        atomicAdd(orow + wc * 64 + j * 16 + l15,
                                  g * (acc[i][j][r] + b2v[j]));
                } else {
                    size_t yoff = (size_t)(slot_tile + rowl) * DM + nt * 256;
                    if (YM == 1) {
                        float* yr = (float*)ybuf + yoff;
#pragma unroll
                        for (int j = 0; j < 4; ++j)
                            yr[wc * 64 + j * 16 + l15] = g * (acc[i][j][r] + b2v[j]);
                    } else {
                        __bf16* yr = (__bf16*)ybuf + yoff;
#pragma unroll
                        for (int j = 0; j < 4; ++j)
                            yr[wc * 64 + j * 16 + l15] =
                                (__bf16)(g * (acc[i][j][r] + b2v[j]));
                    }
                }
            }
        }
    }
}

// ---------------- combine: out[tok] = y[slot0] + y[slot1] ----------------
template<int YM>
__global__ __launch_bounds__(256) void combine_kernel(
        const void* __restrict__ ybuf, const uint32_t* __restrict__ pack,
        const int* __restrict__ pbase, float* __restrict__ out) {
    int tk = blockIdx.x;
    uint32_t pk = pack[tk];
    uint32_t a = pk >> 16, b = pk & 0xffffu;
    size_t sa = (size_t)pbase[a >> 13] + (a & 8191u);
    size_t sb = (size_t)pbase[b >> 13] + (b & 8191u);
    int d = threadIdx.x * 4;
    f32x4 vo;
    if (YM == 1) {
        const float* y = (const float*)ybuf;
        f32x4 va = *(const f32x4*)(y + sa * DM + d);
        f32x4 vb = *(const f32x4*)(y + sb * DM + d);
#pragma unroll
        for (int j = 0; j < 4; ++j) vo[j] = va[j] + vb[j];
    } else {
        const __bf16* y = (const __bf16*)ybuf;
        bf16x4 va = *(const bf16x4*)(y + sa * DM + d);
        bf16x4 vb = *(const bf16x4*)(y + sb * DM + d);
#pragma unroll
        for (int j = 0; j < 4; ++j) vo[j] = (float)va[j] + (float)vb[j];
    }
    *(f32x4*)(out + (size_t)tk * DM + d) = vo;
}

extern "C" void kernel_launch(void* const* d_in, const int* in_sizes, int n_in,
                              void* d_out, int out_size, void* d_ws, size_t ws_size,
                              hipStream_t stream) {
    const float* x      = (const float*)d_in[0];
    const float* gate_w = (const float*)d_in[1];
    const float* gate_b = (const float*)d_in[2];
    const float* w1     = (const float*)d_in[3];
    const float* b1     = (const float*)d_in[4];
    const float* w2     = (const float*)d_in[5];
    const float* b2     = (const float*)d_in[6];
    float* out = (float*)d_out;

    // ws: [counts 64][pbase 64][idx 256K][gate 256K][pack 32K][w1t][w2t][xb][ybuf][hbuf]
    char* wsb = (char*)d_ws;
    int*      counts   = (int*)wsb;
    int*      pbase    = (int*)(wsb + 64);
    int*      idx_list = (int*)(wsb + 128);
    float*    gate_lst = (float*)(wsb + 128 + 262144);
    uint32_t* pack     = (uint32_t*)(wsb + 128 + 524288);
    const size_t FIXED = 557184;
    const size_t W_ELEMS = (size_t)NE * DM * FFNDIM;     // 33,554,432 elems each
    __bf16* w1t = (__bf16*)(wsb + FIXED);
    __bf16* w2t = w1t + W_ELEMS;
    __bf16* xb  = w2t + W_ELEMS;
    char*   dyn = (char*)(xb + (size_t)T_TOKENS * DM);
    const size_t DYNBASE = FIXED + 4 * W_ELEMS + (size_t)T_TOKENS * DM * 2;
    size_t avail = ws_size > DYNBASE ? ws_size - DYNBASE : 0;

    const size_t YB32 = (size_t)SMAX * DM * 4;           // 75.5 MB
    const size_t YB16 = (size_t)SMAX * DM * 2;           // 37.7 MB
    int S, NCH, YM;
    if      (avail >= YB32 + 18432ull * 8192) { S = 18432; NCH = 1; YM = 1; }
    else if (avail >= YB32 + 9216ull * 8192)  { S = 9216;  NCH = 2; YM = 1; }
    else if (avail >= YB16 + 9216ull * 8192)  { S = 9216;  NCH = 2; YM = 2; }
    else if (avail >= YB16 + 4608ull * 8192)  { S = 4608;  NCH = 4; YM = 2; }
    else                                      { S = 2304;  NCH = 8; YM = 0; }
    char*   ybuf = dyn;
    __bf16* hbuf = (__bf16*)(dyn + (YM == 1 ? YB32 : YM == 2 ? YB16 : 0));

    cvt_x_kernel<<<4096, 256, 0, stream>>>(x, xb);
    transpose_cvt_kernel<<<dim3(FFNDIM / 64, DM / 64, NE), 256, 0, stream>>>(
        w1, w1t, DM, FFNDIM);
    transpose_cvt_kernel<<<dim3(DM / 64, FFNDIM / 64, NE), 256, 0, stream>>>(
        w2, w2t, FFNDIM, DM);
    if (YM) zero_counts_kernel<<<1, 64, 0, stream>>>(counts);
    else    zero_out_kernel<<<4096, 256, 0, stream>>>(out, counts);
    router_kernel<<<2048, 256, 0, stream>>>(x, gate_w, gate_b, counts, idx_list,
                                            gate_lst, pack);
    scan_kernel<<<1, 64, 0, stream>>>(counts, pbase);

    int MT = S / 256;
    for (int c = 0; c < NCH; ++c) {
        gemm1_kernel<<<dim3(MT * 16), 512, 0, stream>>>(xb, w1t, b1, counts, pbase,
                                                        idx_list, hbuf, c * S);
        if (YM == 1)
            gemm2_kernel<1><<<dim3(MT * 4), 512, 0, stream>>>(
                hbuf, w2t, b2, counts, pbase, idx_list, gate_lst, out, ybuf, c * S);
        else if (YM == 2)
            gemm2_kernel<2><<<dim3(MT * 4), 512, 0, stream>>>(
                hbuf, w2t, b2, counts, pbase, idx_list, gate_lst, out, ybuf, c * S);
        else
            gemm2_kernel<0><<<dim3(MT * 4), 512, 0, stream>>>(
                hbuf, w2t, b2, counts, pbase, idx_list, gate_lst, out, ybuf, c * S);
    }
    if (YM == 1)
        combine_kernel<1><<<dim3(T_TOKENS), 256, 0, stream>>>(ybuf, pack, pbase, out);
    else if (YM == 2)
        combine_kernel<2><<<dim3(T_TOKENS), 256, 0, stream>>>(ybuf, pack, pbase, out);
}

// Round 5
// 1156.242 us; speedup vs baseline: 1.0940x; 1.0940x over previous
//
#include <hip/hip_runtime.h>
#include <hip/hip_bf16.h>
#include <math.h>
#include <stdint.h>

// SparseMoE: B=4, L=2048 -> T=8192 tokens, D=1024, FFN=4096, E=8, topk=2.
// R5: R4 skeleton + counted-vmcnt ring pipeline (T4): 4-buffer LDS ring, depth-3
// prefetch, ONE raw s_barrier per K-step, s_waitcnt vmcnt(8) steady state (never 0),
// setprio around MFMA cluster. cvt_x fused into router.
#define T_TOKENS 8192
#define DM 1024
#define FFNDIM 4096
#define NE 8
#define CAP 8192
#define SMAX 18432            // >= 16384 + 8*255, 256-aligned

typedef __attribute__((ext_vector_type(8))) __bf16 bf16x8;
typedef __attribute__((ext_vector_type(4))) __bf16 bf16x4;
typedef __attribute__((ext_vector_type(4))) float f32x4;

__device__ __forceinline__ float gelu_exact(float v) {
    return 0.5f * v * (1.0f + erff(v * 0.70710678118654752440f));
}

union PK8 { __bf16 h[8]; uint4 v; };

// 16B global->LDS DMA. LDS dest is WAVE-UNIFORM base; HW writes base + lane*16.
// Global src is per-lane (gather + swizzle live on the source side).
__device__ __forceinline__ void gload16(const void* g, void* l) {
    __builtin_amdgcn_global_load_lds(
        (const __attribute__((address_space(1))) uint32_t*)g,
        (__attribute__((address_space(3))) uint32_t*)l, 16, 0, 0);
}

// Bijective XCD-chunked swizzle (m204 form, valid for any nwg).
__device__ __forceinline__ int xcd_swz(int nwg) {
    int orig = blockIdx.x;
    int xcd = orig & 7, loc = orig >> 3;
    int q = nwg >> 3, r = nwg & 7;
    int base = (xcd < r) ? xcd * (q + 1) : r * (q + 1) + (xcd - r) * q;
    return base + loc;
}

// ---------------- tiny utility kernels ----------------
__global__ void zero_counts_kernel(int* __restrict__ counts) {
    if (threadIdx.x < NE) counts[threadIdx.x] = 0;
}

__global__ __launch_bounds__(256) void zero_out_kernel(float* __restrict__ out,
                                                       int* __restrict__ counts) {
    size_t i = (size_t)blockIdx.x * 256 + threadIdx.x;
    uint4 z = make_uint4(0u, 0u, 0u, 0u);
    uint4* p = (uint4*)out + i * 2;
    p[0] = z; p[1] = z;
    if (blockIdx.x == 0 && threadIdx.x < NE) counts[threadIdx.x] = 0;
}

// ---------------- prepass: w [E][K][N] f32 -> wt [E][N][K] bf16 ----------------
__global__ __launch_bounds__(256) void transpose_cvt_kernel(
        const float* __restrict__ w, __bf16* __restrict__ wt, int K, int N) {
    __shared__ __bf16 tile[64][72];
    int ntb = blockIdx.x, ktb = blockIdx.y, e = blockIdx.z;
    const float* src = w + ((size_t)e * K + (size_t)ktb * 64) * N + ntb * 64;
    int t = threadIdx.x;
    int tx = t & 15, ty = t >> 4;
#pragma unroll
    for (int rr = 0; rr < 4; ++rr) {
        int r = ty + rr * 16;
        f32x4 v = *(const f32x4*)(src + (size_t)r * N + tx * 4);
#pragma unroll
        for (int j = 0; j < 4; ++j) tile[tx * 4 + j][r] = (__bf16)v[j];
    }
    __syncthreads();
    int ow = t & 7, oy = t >> 3;
#pragma unroll
    for (int rr = 0; rr < 2; ++rr) {
        int n = oy + rr * 32;
        uint4 val = *(const uint4*)&tile[n][ow * 8];
        *(uint4*)(wt + ((size_t)e * N + (size_t)ntb * 64 + n) * K
                  + (size_t)ktb * 64 + ow * 8) = val;
    }
}

// ---------------- router (+ fused x -> bf16 conversion) ----------------
__global__ __launch_bounds__(256) void router_kernel(
        const float* __restrict__ x, const float* __restrict__ gate_w,
        const float* __restrict__ gate_b, int* __restrict__ counts,
        int* __restrict__ idx_list, float* __restrict__ gate_list,
        uint32_t* __restrict__ pack, __bf16* __restrict__ xb) {
    int wave = threadIdx.x >> 6, lane = threadIdx.x & 63;
    int tk = blockIdx.x * 4 + wave;
    const float* xr = x + (size_t)tk * DM;
    float acc[NE];
#pragma unroll
    for (int e = 0; e < NE; ++e) acc[e] = 0.f;
#pragma unroll
    for (int i = 0; i < DM / 64; ++i) {
        int d = i * 64 + lane;
        float xv = xr[d];
        xb[(size_t)tk * DM + d] = (__bf16)xv;            // fused cvt_x
        f32x4 g0v = *(const f32x4*)(gate_w + d * NE);
        f32x4 g1v = *(const f32x4*)(gate_w + d * NE + 4);
#pragma unroll
        for (int e = 0; e < 4; ++e) { acc[e] += xv * g0v[e]; acc[4 + e] += xv * g1v[e]; }
    }
#pragma unroll
    for (int e = 0; e < NE; ++e) {
#pragma unroll
        for (int m = 32; m > 0; m >>= 1) acc[e] += __shfl_xor(acc[e], m, 64);
    }
    if (lane == 0) {
        float v0 = -INFINITY, v1 = -INFINITY;
        int i0 = 0, i1 = 0;
#pragma unroll
        for (int e = 0; e < NE; ++e) {
            float l = acc[e] + gate_b[e];
            if (l > v0) { v1 = v0; i1 = i0; v0 = l; i0 = e; }
            else if (l > v1) { v1 = l; i1 = e; }
        }
        float g0 = 1.f / (1.f + expf(v1 - v0));
        float g1 = 1.f - g0;
        int p0 = atomicAdd(&counts[i0], 1);
        idx_list[i0 * CAP + p0] = tk;
        gate_list[i0 * CAP + p0] = g0;
        int p1 = atomicAdd(&counts[i1], 1);
        idx_list[i1 * CAP + p1] = tk;
        gate_list[i1 * CAP + p1] = g1;
        pack[tk] = ((uint32_t)((i0 << 13) | p0) << 16) | (uint32_t)((i1 << 13) | p1);
    }
}

// ---------------- scan: 256-aligned prefix ----------------
__global__ void scan_kernel(const int* __restrict__ counts, int* __restrict__ pbase) {
    if (threadIdx.x == 0 && blockIdx.x == 0) {
        int s = 0;
        for (int e = 0; e < NE; ++e) { pbase[e] = s; s += (counts[e] + 255) & ~255; }
        pbase[NE] = s;
    }
}

__device__ __forceinline__ int find_expert(const int* pbase, int slot_tile) {
    int e = 0;
#pragma unroll
    for (int k = 0; k < NE - 1; ++k)
        if (pbase[k + 1] <= slot_tile) e = k + 1;
    return e;
}

// ======== unified 256x256 GEMM core: 8 waves, BK=32, 4-buffer counted-vmcnt ring =====
// LDS: Al/Bl [4][256*32] bf16 = 128 KB -> 1 block/CU. Per stage each WAVE issues 4
// global_load_lds (2 A + 2 B) -> vmcnt ledger: depth-3 in flight = 12; vmcnt(8)
// guarantees the oldest stage complete (in-order completion; any compiler-inserted
// vmem ops only make the wait stricter). ONE raw s_barrier per step:
//   vmcnt(N) ; s_barrier ; stage(st+3) [overwrites buf last read at step st-1,
//   which every wave finished before reaching THIS barrier] ; ds_read+MFMA(st).
// XOR involution swizzle (source-side + read-side) as verified in R4.

#define RING_WAIT(rem_)                                              \
    if ((rem_) >= 2)      asm volatile("s_waitcnt vmcnt(8)" ::: "memory"); \
    else if ((rem_) == 1) asm volatile("s_waitcnt vmcnt(4)" ::: "memory"); \
    else                  asm volatile("s_waitcnt vmcnt(0)" ::: "memory");

// ---------------- gemm1: h = gelu(xb[tok] @ w1t[e] + b1[e]) ----------------
__global__ __launch_bounds__(512, 2) void gemm1_kernel(
        const __bf16* __restrict__ xb, const __bf16* __restrict__ w1t,
        const float* __restrict__ b1, const int* __restrict__ counts,
        const int* __restrict__ pbase, const int* __restrict__ idx_list,
        __bf16* __restrict__ h, int chunk_start) {
    __shared__ __bf16 Al[4][256 * 32];
    __shared__ __bf16 Bl[4][256 * 32];

    int wid = xcd_swz(gridDim.x);
    int mtl = wid >> 4, nt = wid & 15;          // nt-fastest: A reused across nt in L2

    int slot_tile = chunk_start + mtl * 256;
    if (slot_tile >= pbase[NE]) return;
    int e = find_expert(pbase, slot_tile);
    int cnt = counts[e];
    int loc = slot_tile - pbase[e];
    if (loc >= cnt) return;

    int t = threadIdx.x, lane = t & 63, wave = t >> 6;

    const char* asrc[2];
    const char* bsrc[2];
    uint32_t dofs[2];
#pragma unroll
    for (int q = 0; q < 2; ++q) {
        int row = (wave * 2 + q) * 16 + (lane >> 2);
        int ch  = lane & 3;
        int sw  = ((ch ^ ((row >> 1) & 3)) << 4);
        int lc = loc + row; if (lc > cnt - 1) lc = cnt - 1;
        int tok = idx_list[e * CAP + lc];
        asrc[q] = (const char*)(xb + (size_t)tok * DM) + sw;
        bsrc[q] = (const char*)(w1t + ((size_t)e * FFNDIM + nt * 256 + row) * DM) + sw;
        dofs[q] = (uint32_t)(wave * 2 + q) * 1024;   // wave-uniform LDS byte offset
    }

    int wr = wave >> 2, wc = wave & 3;               // 2x4 wave grid: 128m x 64n each
    int l15 = lane & 15, quad = lane >> 4;

    f32x4 acc[8][4];
#pragma unroll
    for (int i = 0; i < 8; ++i)
#pragma unroll
        for (int j = 0; j < 4; ++j) acc[i][j] = f32x4{0.f, 0.f, 0.f, 0.f};

    // prologue: stage steps 0..2 into bufs 0..2 (12 vmem instrs/wave in flight)
#pragma unroll
    for (int s = 0; s < 3; ++s)
#pragma unroll
        for (int q = 0; q < 2; ++q) {
            gload16(asrc[q] + s * 64, (char*)Al[s] + dofs[q]);
            gload16(bsrc[q] + s * 64, (char*)Bl[s] + dofs[q]);
        }

    const int NSTEP = DM / 32;                       // 32 steps
#pragma unroll 1
    for (int st = 0; st < NSTEP; ++st) {
        int rem = NSTEP - 1 - st;
        RING_WAIT(rem);
        __builtin_amdgcn_s_barrier();
        if (st + 3 < NSTEP) {
            int s = st + 3, b = s & 3, off = s * 64;
#pragma unroll
            for (int q = 0; q < 2; ++q) {
                gload16(asrc[q] + off, (char*)Al[b] + dofs[q]);
                gload16(bsrc[q] + off, (char*)Bl[b] + dofs[q]);
            }
        }
        const __bf16* A = Al[st & 3];
        const __bf16* B = Bl[st & 3];
        bf16x8 af[8], bfr[4];
#pragma unroll
        for (int i = 0; i < 8; ++i) {
            int m = wr * 128 + i * 16 + l15;
            af[i] = *(const bf16x8*)(A + m * 32 + ((quad ^ ((m >> 1) & 3)) << 3));
        }
#pragma unroll
        for (int j = 0; j < 4; ++j) {
            int n = wc * 64 + j * 16 + l15;
            bfr[j] = *(const bf16x8*)(B + n * 32 + ((quad ^ ((n >> 1) & 3)) << 3));
        }
        __builtin_amdgcn_s_setprio(1);
#pragma unroll
        for (int i = 0; i < 8; ++i)
#pragma unroll
            for (int j = 0; j < 4; ++j)
                acc[i][j] = __builtin_amdgcn_mfma_f32_16x16x32_bf16(
                    af[i], bfr[j], acc[i][j], 0, 0, 0);
        __builtin_amdgcn_s_setprio(0);
    }

    float bias[4];
#pragma unroll
    for (int j = 0; j < 4; ++j)
        bias[j] = b1[(size_t)e * FFNDIM + nt * 256 + wc * 64 + j * 16 + l15];
#pragma unroll
    for (int i = 0; i < 8; ++i) {
#pragma unroll
        for (int r = 0; r < 4; ++r) {
            int rowl = wr * 128 + i * 16 + quad * 4 + r;
            if (loc + rowl < cnt) {
                size_t hoff = (size_t)(mtl * 256 + rowl) * FFNDIM + nt * 256;
#pragma unroll
                for (int j = 0; j < 4; ++j) {
                    float v = acc[i][j][r] + bias[j];
                    h[hoff + wc * 64 + j * 16 + l15] = (__bf16)gelu_exact(v);
                }
            }
        }
    }
}

// ---------------- gemm2: y[slot] = gate*(h_slot @ w2t[e] + b2) ----------------
// YM: 0 = atomicAdd into out, 1 = f32 ybuf, 2 = bf16 ybuf.
template<int YM>
__global__ __launch_bounds__(512, 2) void gemm2_kernel(
        const __bf16* __restrict__ h, const __bf16* __restrict__ w2t,
        const float* __restrict__ b2, const int* __restrict__ counts,
        const int* __restrict__ pbase, const int* __restrict__ idx_list,
        const float* __restrict__ gate_list, float* __restrict__ out,
        void* __restrict__ ybuf, int chunk_start) {
    __shared__ __bf16 Al[4][256 * 32];
    __shared__ __bf16 Bl[4][256 * 32];

    int wid = xcd_swz(gridDim.x);
    int mtl = wid >> 2, nt = wid & 3;               // nt-fastest (4 nt over DM)

    int slot_tile = chunk_start + mtl * 256;
    if (slot_tile >= pbase[NE]) return;
    int e = find_expert(pbase, slot_tile);
    int cnt = counts[e];
    int loc = slot_tile - pbase[e];
    if (loc >= cnt) return;

    int t = threadIdx.x, lane = t & 63, wave = t >> 6;

    const char* asrc[2];
    const char* bsrc[2];
    uint32_t dofs[2];
#pragma unroll
    for (int q = 0; q < 2; ++q) {
        int row = (wave * 2 + q) * 16 + (lane >> 2);
        int ch  = lane & 3;
        int sw  = ((ch ^ ((row >> 1) & 3)) << 4);
        asrc[q] = (const char*)(h + (size_t)(mtl * 256 + row) * FFNDIM) + sw;
        bsrc[q] = (const char*)(w2t + ((size_t)e * DM + nt * 256 + row) * FFNDIM) + sw;
        dofs[q] = (uint32_t)(wave * 2 + q) * 1024;
    }

    int wr = wave >> 2, wc = wave & 3;
    int l15 = lane & 15, quad = lane >> 4;

    f32x4 acc[8][4];
#pragma unroll
    for (int i = 0; i < 8; ++i)
#pragma unroll
        for (int j = 0; j < 4; ++j) acc[i][j] = f32x4{0.f, 0.f, 0.f, 0.f};

#pragma unroll
    for (int s = 0; s < 3; ++s)
#pragma unroll
        for (int q = 0; q < 2; ++q) {
            gload16(asrc[q] + s * 64, (char*)Al[s] + dofs[q]);
            gload16(bsrc[q] + s * 64, (char*)Bl[s] + dofs[q]);
        }

    const int NSTEP = FFNDIM / 32;                   // 128 steps
#pragma unroll 1
    for (int st = 0; st < NSTEP; ++st) {
        int rem = NSTEP - 1 - st;
        RING_WAIT(rem);
        __builtin_amdgcn_s_barrier();
        if (st + 3 < NSTEP) {
            int s = st + 3, b = s & 3, off = s * 64;
#pragma unroll
            for (int q = 0; q < 2; ++q) {
                gload16(asrc[q] + off, (char*)Al[b] + dofs[q]);
                gload16(bsrc[q] + off, (char*)Bl[b] + dofs[q]);
            }
        }
        const __bf16* A = Al[st & 3];
        const __bf16* B = Bl[st & 3];
        bf16x8 af[8], bfr[4];
#pragma unroll
        for (int i = 0; i < 8; ++i) {
            int m = wr * 128 + i * 16 + l15;
            af[i] = *(const bf16x8*)(A + m * 32 + ((quad ^ ((m >> 1) & 3)) << 3));
        }
#pragma unroll
        for (int j = 0; j < 4; ++j) {
            int n = wc * 64 + j * 16 + l15;
            bfr[j] = *(const bf16x8*)(B + n * 32 + ((quad ^ ((n >> 1) & 3)) << 3));
        }
        __builtin_amdgcn_s_setprio(1);
#pragma unroll
        for (int i = 0; i < 8; ++i)
#pragma unroll
            for (int j = 0; j < 4; ++j)
                acc[i][j] = __builtin_amdgcn_mfma_f32_16x16x32_bf16(
                    af[i], bfr[j], acc[i][j], 0, 0, 0);
        __builtin_amdgcn_s_setprio(0);
    }

    float b2v[4];
#pragma unroll
    for (int j = 0; j < 4; ++j)
        b2v[j] = b2[(size_t)e * DM + nt * 256 + wc * 64 + j * 16 + l15];
#pragma unroll
    for (int i = 0; i < 8; ++i) {
#pragma unroll
        for (int r = 0; r < 4; ++r) {
            int rowl = wr * 128 + i * 16 + quad * 4 + r;
            int local = loc + rowl;
            if (local < cnt) {
                float g = gate_list[e * CAP + local];
                if (YM == 0) {
                    int tok = idx_list[e * CAP + local];
                    float* orow = out + (size_t)tok * DM + nt * 256;
#pragma unroll
                    for (int j = 0; j < 4; ++j)
                        atomicAdd(orow + wc * 64 + j * 16 + l15,
                                  g * (acc[i][j][r] + b2v[j]));
                } else {
                    size_t yoff = (size_t)(slot_tile + rowl) * DM + nt * 256;
                    if (YM == 1) {
                        float* yr = (float*)ybuf + yoff;
#pragma unroll
                        for (int j = 0; j < 4; ++j)
                            yr[wc * 64 + j * 16 + l15] = g * (acc[i][j][r] + b2v[j]);
                    } else {
                        __bf16* yr = (__bf16*)ybuf + yoff;
#pragma unroll
                        for (int j = 0; j < 4; ++j)
                            yr[wc * 64 + j * 16 + l15] =
                                (__bf16)(g * (acc[i][j][r] + b2v[j]));
                    }
                }
            }
        }
    }
}

// ---------------- combine: out[tok] = y[slot0] + y[slot1] ----------------
template<int YM>
__global__ __launch_bounds__(256) void combine_kernel(
        const void* __restrict__ ybuf, const uint32_t* __restrict__ pack,
        const int* __restrict__ pbase, float* __restrict__ out) {
    int tk = blockIdx.x;
    uint32_t pk = pack[tk];
    uint32_t a = pk >> 16, b = pk & 0xffffu;
    size_t sa = (size_t)pbase[a >> 13] + (a & 8191u);
    size_t sb = (size_t)pbase[b >> 13] + (b & 8191u);
    int d = threadIdx.x * 4;
    f32x4 vo;
    if (YM == 1) {
        const float* y = (const float*)ybuf;
        f32x4 va = *(const f32x4*)(y + sa * DM + d);
        f32x4 vb = *(const f32x4*)(y + sb * DM + d);
#pragma unroll
        for (int j = 0; j < 4; ++j) vo[j] = va[j] + vb[j];
    } else {
        const __bf16* y = (const __bf16*)ybuf;
        bf16x4 va = *(const bf16x4*)(y + sa * DM + d);
        bf16x4 vb = *(const bf16x4*)(y + sb * DM + d);
#pragma unroll
        for (int j = 0; j < 4; ++j) vo[j] = (float)va[j] + (float)vb[j];
    }
    *(f32x4*)(out + (size_t)tk * DM + d) = vo;
}

extern "C" void kernel_launch(void* const* d_in, const int* in_sizes, int n_in,
                              void* d_out, int out_size, void* d_ws, size_t ws_size,
                              hipStream_t stream) {
    const float* x      = (const float*)d_in[0];
    const float* gate_w = (const float*)d_in[1];
    const float* gate_b = (const float*)d_in[2];
    const float* w1     = (const float*)d_in[3];
    const float* b1     = (const float*)d_in[4];
    const float* w2     = (const float*)d_in[5];
    const float* b2     = (const float*)d_in[6];
    float* out = (float*)d_out;

    // ws: [counts 64][pbase 64][idx 256K][gate 256K][pack 32K][w1t][w2t][xb][ybuf][hbuf]
    char* wsb = (char*)d_ws;
    int*      counts   = (int*)wsb;
    int*      pbase    = (int*)(wsb + 64);
    int*      idx_list = (int*)(wsb + 128);
    float*    gate_lst = (float*)(wsb + 128 + 262144);
    uint32_t* pack     = (uint32_t*)(wsb + 128 + 524288);
    const size_t FIXED = 557184;
    const size_t W_ELEMS = (size_t)NE * DM * FFNDIM;     // 33,554,432 elems each
    __bf16* w1t = (__bf16*)(wsb + FIXED);
    __bf16* w2t = w1t + W_ELEMS;
    __bf16* xb  = w2t + W_ELEMS;
    char*   dyn = (char*)(xb + (size_t)T_TOKENS * DM);
    const size_t DYNBASE = FIXED + 4 * W_ELEMS + (size_t)T_TOKENS * DM * 2;
    size_t avail = ws_size > DYNBASE ? ws_size - DYNBASE : 0;

    const size_t YB32 = (size_t)SMAX * DM * 4;           // 75.5 MB
    const size_t YB16 = (size_t)SMAX * DM * 2;           // 37.7 MB
    int S, NCH, YM;
    if      (avail >= YB32 + 18432ull * 8192) { S = 18432; NCH = 1; YM = 1; }
    else if (avail >= YB32 + 9216ull * 8192)  { S = 9216;  NCH = 2; YM = 1; }
    else if (avail >= YB16 + 9216ull * 8192)  { S = 9216;  NCH = 2; YM = 2; }
    else if (avail >= YB16 + 4608ull * 8192)  { S = 4608;  NCH = 4; YM = 2; }
    else                                      { S = 2304;  NCH = 8; YM = 0; }
    char*   ybuf = dyn;
    __bf16* hbuf = (__bf16*)(dyn + (YM == 1 ? YB32 : YM == 2 ? YB16 : 0));

    transpose_cvt_kernel<<<dim3(FFNDIM / 64, DM / 64, NE), 256, 0, stream>>>(
        w1, w1t, DM, FFNDIM);
    transpose_cvt_kernel<<<dim3(DM / 64, FFNDIM / 64, NE), 256, 0, stream>>>(
        w2, w2t, FFNDIM, DM);
    if (YM) zero_counts_kernel<<<1, 64, 0, stream>>>(counts);
    else    zero_out_kernel<<<4096, 256, 0, stream>>>(out, counts);
    router_kernel<<<2048, 256, 0, stream>>>(x, gate_w, gate_b, counts, idx_list,
                                            gate_lst, pack, xb);
    scan_kernel<<<1, 64, 0, stream>>>(counts, pbase);

    int MT = S / 256;
    for (int c = 0; c < NCH; ++c) {
        gemm1_kernel<<<dim3(MT * 16), 512, 0, stream>>>(xb, w1t, b1, counts, pbase,
                                                        idx_list, hbuf, c * S);
        if (YM == 1)
            gemm2_kernel<1><<<dim3(MT * 4), 512, 0, stream>>>(
                hbuf, w2t, b2, counts, pbase, idx_list, gate_lst, out, ybuf, c * S);
        else if (YM == 2)
            gemm2_kernel<2><<<dim3(MT * 4), 512, 0, stream>>>(
                hbuf, w2t, b2, counts, pbase, idx_list, gate_lst, out, ybuf, c * S);
        else
            gemm2_kernel<0><<<dim3(MT * 4), 512, 0, stream>>>(
                hbuf, w2t, b2, counts, pbase, idx_list, gate_lst, out, ybuf, c * S);
    }
    if (YM == 1)
        combine_kernel<1><<<dim3(T_TOKENS), 256, 0, stream>>>(ybuf, pack, pbase, out);
    else if (YM == 2)
        combine_kernel<2><<<dim3(T_TOKENS), 256, 0, stream>>>(ybuf, pack, pbase, out);
}